// Round 1
// baseline (2512.218 us; speedup 1.0000x reference)
//
#include <hip/hip_runtime.h>
#include <hip/hip_bf16.h>

using bf16 = __hip_bfloat16;
typedef __attribute__((ext_vector_type(8))) short short8;
typedef __attribute__((ext_vector_type(4))) float f32x4;

#define LDD 40
// XOR swizzle of the k-column (elements) within a 32-wide LDS row, varies with row>>3
#define SW(r, c) ((c) ^ ((((r) >> 3) & 3) << 3))

__device__ __forceinline__ float gelu_exact(float v) {
    return 0.5f * v * (1.0f + erff(v * 0.70710678118654752f));
}

// ---- block reduce helpers (256 threads = 4 waves) ----
__device__ __forceinline__ float blk_sum(float v, float* red) {
#pragma unroll
    for (int o = 32; o > 0; o >>= 1) v += __shfl_down(v, o, 64);
    int wv = threadIdx.x >> 6;
    __syncthreads();
    if ((threadIdx.x & 63) == 0) red[wv] = v;
    __syncthreads();
    return red[0] + red[1] + red[2] + red[3];
}
__device__ __forceinline__ float blk_max(float v, float* red) {
#pragma unroll
    for (int o = 32; o > 0; o >>= 1) v = fmaxf(v, __shfl_down(v, o, 64));
    int wv = threadIdx.x >> 6;
    __syncthreads();
    if ((threadIdx.x & 63) == 0) red[wv] = v;
    __syncthreads();
    return fmaxf(fmaxf(red[0], red[1]), fmaxf(red[2], red[3]));
}

// ---- LayerNorm over D=768, one block per (n,l) row, f32 in -> bf16 out ----
__global__ __launch_bounds__(256) void ln_kernel(const float* __restrict__ x,
                                                 const float* __restrict__ g,
                                                 const float* __restrict__ b,
                                                 bf16* __restrict__ y) {
    __shared__ float red[4];
    size_t base = (size_t)blockIdx.x * 768;
    int t = threadIdx.x;
    float v0 = x[base + t], v1 = x[base + t + 256], v2 = x[base + t + 512];
    float s = blk_sum(v0 + v1 + v2, red);
    float mean = s * (1.0f / 768.0f);
    float d0 = v0 - mean, d1 = v1 - mean, d2 = v2 - mean;
    float sq = blk_sum(d0 * d0 + d1 * d1 + d2 * d2, red);
    float rstd = rsqrtf(sq * (1.0f / 768.0f) + 1e-6f);
    y[base + t]       = __float2bfloat16(d0 * rstd * g[t]       + b[t]);
    y[base + t + 256] = __float2bfloat16(d1 * rstd * g[t + 256] + b[t + 256]);
    y[base + t + 512] = __float2bfloat16(d2 * rstd * g[t + 512] + b[t + 512]);
}

// ---- f32 -> bf16 cast ----
__global__ __launch_bounds__(256) void cast_kernel(const float* __restrict__ s,
                                                   bf16* __restrict__ d, int n) {
    int i = blockIdx.x * 256 + threadIdx.x;
    if (i < n) d[i] = __float2bfloat16(s[i]);
}

// ---- GEMM: C[M,N] = A[M,K] * B (+epilogue). 128x128 tile, BK=32, 256 thr ----
// B_IS_NK: B is [N,K] row-major (ldb=K); else B is [K,N] row-major (ldb=N).
// MODE 0: C=f32, +bias[row]
// MODE 1: C=f32, +bias[row] + resid[flat]
// MODE 2: C=bf16, gelu(v + bias[col])
// MODE 3: C=f32, +bias[col] + resid[flat]
template <int MODE, bool B_IS_NK>
__global__ __launch_bounds__(256) void gemm_kernel(
    const bf16* __restrict__ A, const bf16* __restrict__ B,
    const float* __restrict__ bias, const float* __restrict__ resid,
    void* __restrict__ Cv, int M, int N, int K, long sB, long sC, long sR) {
    __shared__ unsigned short As[128][LDD];
    __shared__ unsigned short Bs[128][LDD];
    const int tid = threadIdx.x;
    const int bn = blockIdx.x, bm = blockIdx.y, bz = blockIdx.z;
    const bf16* Bp = B + (size_t)bz * sB;
    const int lane = tid & 63, wave = tid >> 6;
    const int wm = (wave >> 1) * 64, wn = (wave & 1) * 64;
    const int frow = lane & 15, fk = (lane >> 4) << 3;
    const int lda = K;
    const int ldb = B_IS_NK ? K : N;

    f32x4 acc[4][4];
#pragma unroll
    for (int mi = 0; mi < 4; mi++)
#pragma unroll
        for (int ni = 0; ni < 4; ni++)
#pragma unroll
            for (int r = 0; r < 4; r++) acc[mi][ni][r] = 0.0f;

    for (int kt = 0; kt < K; kt += 32) {
        // A tile: 128 rows x 32 k, vectorized 8-bf16 loads
#pragma unroll
        for (int i = 0; i < 2; i++) {
            int gidx = i * 256 + tid;
            int r = gidx >> 2, kg = (gidx & 3) << 3;
            uint4 val = *(const uint4*)(A + (size_t)(bm * 128 + r) * lda + kt + kg);
            *(uint4*)&As[r][SW(r, kg)] = val;
        }
        if (B_IS_NK) {
#pragma unroll
            for (int i = 0; i < 2; i++) {
                int gidx = i * 256 + tid;
                int r = gidx >> 2, kg = (gidx & 3) << 3;
                int gn = bn * 128 + r;
                uint4 val = {0, 0, 0, 0};
                if (gn < N) val = *(const uint4*)(Bp + (size_t)gn * ldb + kt + kg);
                *(uint4*)&Bs[r][SW(r, kg)] = val;
            }
        } else {
#pragma unroll
            for (int i = 0; i < 2; i++) {
                int gidx = i * 256 + tid;
                int kk = gidx >> 4, c8 = (gidx & 15) << 3;
                int gc = bn * 128 + c8;
                uint4 val = {0, 0, 0, 0};
                if (gc + 8 <= N) val = *(const uint4*)(Bp + (size_t)(kt + kk) * ldb + gc);
                union { uint4 v; unsigned short u[8]; } u;
                u.v = val;
#pragma unroll
                for (int jj = 0; jj < 8; jj++) Bs[c8 + jj][SW(c8 + jj, kk)] = u.u[jj];
            }
        }
        __syncthreads();
        short8 af[4], bfr[4];
#pragma unroll
        for (int mi = 0; mi < 4; mi++) {
            int r = wm + mi * 16 + frow;
            af[mi] = *(const short8*)&As[r][SW(r, fk)];
        }
#pragma unroll
        for (int ni = 0; ni < 4; ni++) {
            int r = wn + ni * 16 + frow;
            bfr[ni] = *(const short8*)&Bs[r][SW(r, fk)];
        }
#pragma unroll
        for (int mi = 0; mi < 4; mi++)
#pragma unroll
            for (int ni = 0; ni < 4; ni++)
                acc[mi][ni] = __builtin_amdgcn_mfma_f32_16x16x32_bf16(
                    af[mi], bfr[ni], acc[mi][ni], 0, 0, 0);
        __syncthreads();
    }

    float* Cf = (float*)Cv + (size_t)bz * sC;
    bf16* Cb = (bf16*)Cv + (size_t)bz * sC;
    const float* Rp = resid ? (resid + (size_t)bz * sR) : nullptr;
#pragma unroll
    for (int mi = 0; mi < 4; mi++)
#pragma unroll
        for (int ni = 0; ni < 4; ni++)
#pragma unroll
            for (int r = 0; r < 4; r++) {
                int row = bm * 128 + wm + mi * 16 + ((lane >> 4) << 2) + r;
                int col = bn * 128 + wn + ni * 16 + frow;
                if (col < N) {
                    float v = acc[mi][ni][r];
                    size_t idx = (size_t)row * N + col;
                    if (MODE == 0) Cf[idx] = v + bias[row];
                    else if (MODE == 1) Cf[idx] = v + bias[row] + Rp[idx];
                    else if (MODE == 2) Cb[idx] = __float2bfloat16(gelu_exact(v + bias[col]));
                    else Cf[idx] = v + bias[col] + Rp[idx];
                }
            }
}

// ---- row softmax over L=3136, in-place, one block per row ----
__global__ __launch_bounds__(256) void softmax_rows(float* __restrict__ d) {
    __shared__ float buf[3136];
    __shared__ float red[4];
    size_t base = (size_t)blockIdx.x * 3136;
    float mx = -1e30f;
    for (int i = threadIdx.x; i < 3136; i += 256) {
        float v = d[base + i];
        buf[i] = v;
        mx = fmaxf(mx, v);
    }
    mx = blk_max(mx, red);
    float sm = 0.f;
    for (int i = threadIdx.x; i < 3136; i += 256) {
        float e = expf(buf[i] - mx);
        buf[i] = e;
        sm += e;
    }
    sm = blk_sum(sm, red);
    float inv = 1.0f / sm;
    for (int i = threadIdx.x; i < 3136; i += 256) d[base + i] = buf[i] * inv;
}

// ---- column softmax over 96 channels within each head, in-place ----
// grid: (13, N*H); thread handles one spatial column l
__global__ __launch_bounds__(256) void softmax_q(float* __restrict__ d) {
    int nh = blockIdx.y;
    int l = blockIdx.x * 256 + threadIdx.x;
    if (l >= 3136) return;
    float* base = d + (size_t)nh * 96 * 3136 + l;
    float v[96];
    float mx = -1e30f;
#pragma unroll
    for (int i = 0; i < 96; i++) {
        v[i] = base[(size_t)i * 3136];
        mx = fmaxf(mx, v[i]);
    }
    float sm = 0.f;
#pragma unroll
    for (int i = 0; i < 96; i++) {
        v[i] = expf(v[i] - mx);
        sm += v[i];
    }
    float inv = 1.0f / sm;
#pragma unroll
    for (int i = 0; i < 96; i++) base[(size_t)i * 3136] = v[i] * inv;
}

// ---- context[nh,96,48] += kh[nh,96,L) * vh[nh,48,L)^T over L chunk ----
// grid: (2, N*H), each block covers 1568 l's; atomicAdd partials
__global__ __launch_bounds__(256) void context_kernel(const float* __restrict__ kh,
                                                      const float* __restrict__ vh,
                                                      float* __restrict__ ctx) {
    __shared__ float khs[96][33];
    __shared__ float vhs[48][33];
    int nh = blockIdx.y;
    const float* kb = kh + (size_t)nh * 96 * 3136;
    const float* vb = vh + (size_t)nh * 48 * 3136;
    int t = threadIdx.x;
    int rr[18], cc[18];
#pragma unroll
    for (int j = 0; j < 18; j++) {
        int o = t + 256 * j;
        rr[j] = o / 48;
        cc[j] = o - rr[j] * 48;
    }
    float acc[18];
#pragma unroll
    for (int j = 0; j < 18; j++) acc[j] = 0.f;
    int l0 = blockIdx.x * 1568;
    for (int ls = l0; ls < l0 + 1568; ls += 32) {
        __syncthreads();
#pragma unroll
        for (int j = 0; j < 12; j++) {
            int idx = t + 256 * j;
            int r = idx >> 5, c = idx & 31;
            khs[r][c] = kb[(size_t)r * 3136 + ls + c];
        }
#pragma unroll
        for (int j = 0; j < 6; j++) {
            int idx = t + 256 * j;
            int r = idx >> 5, c = idx & 31;
            vhs[r][c] = vb[(size_t)r * 3136 + ls + c];
        }
        __syncthreads();
#pragma unroll
        for (int ll = 0; ll < 32; ll++)
#pragma unroll
            for (int j = 0; j < 18; j++) acc[j] += khs[rr[j]][ll] * vhs[cc[j]][ll];
    }
    float* cb = ctx + (size_t)nh * 4608;
#pragma unroll
    for (int j = 0; j < 18; j++) atomicAdd(&cb[t + 256 * j], acc[j]);
}

// ---- att[nh,48,L] = ctx[nh,:,:]^T @ qh[nh,96,L], bf16 out ----
__global__ __launch_bounds__(256) void att_kernel(const float* __restrict__ ctx,
                                                  const float* __restrict__ qh,
                                                  bf16* __restrict__ att) {
    __shared__ float ctxs[4608];
    int nh = blockIdx.y;
#pragma unroll
    for (int j = 0; j < 18; j++)
        ctxs[threadIdx.x + 256 * j] = ctx[(size_t)nh * 4608 + threadIdx.x + 256 * j];
    __syncthreads();
    int l = blockIdx.x * 256 + threadIdx.x;
    if (l >= 3136) return;
    const float* qb = qh + (size_t)nh * 96 * 3136 + l;
    float q[96];
#pragma unroll
    for (int i = 0; i < 96; i++) q[i] = qb[(size_t)i * 3136];
    bf16* ob = att + (size_t)nh * 48 * 3136 + l;
#pragma unroll 1
    for (int v = 0; v < 48; v++) {
        float s = 0.f;
#pragma unroll
        for (int k = 0; k < 96; k++) s += ctxs[k * 48 + v] * q[k];
        ob[(size_t)v * 3136] = __float2bfloat16(s);
    }
}

extern "C" void kernel_launch(void* const* d_in, const int* in_sizes, int n_in,
                              void* d_out, int out_size, void* d_ws, size_t ws_size,
                              hipStream_t stream) {
    (void)in_sizes; (void)n_in; (void)out_size; (void)ws_size;
    const float* x     = (const float*)d_in[0];
    const float* ln1_g = (const float*)d_in[1];
    const float* ln1_b = (const float*)d_in[2];
    const float* Wk    = (const float*)d_in[3];
    const float* bk    = (const float*)d_in[4];
    const float* Wq    = (const float*)d_in[5];
    const float* bq    = (const float*)d_in[6];
    const float* Wv    = (const float*)d_in[7];
    const float* bv    = (const float*)d_in[8];
    const float* Wr    = (const float*)d_in[9];
    const float* br    = (const float*)d_in[10];
    const float* ln2_g = (const float*)d_in[11];
    const float* ln2_b = (const float*)d_in[12];
    const float* W1    = (const float*)d_in[13];
    const float* b1    = (const float*)d_in[14];
    const float* W2    = (const float*)d_in[15];
    const float* b2    = (const float*)d_in[16];

    const int Nb = 16, L = 3136, D = 768, K = 768, V = 384, M = 3072, H = 8;
    const size_t LD = (size_t)L * D;

    char* w = (char*)d_ws;
    size_t off = 0;
    auto alloc = [&](size_t bytes) {
        char* p = w + off;
        off = (off + bytes + 255) & ~(size_t)255;
        return p;
    };
    float* Keys    = (float*)alloc((size_t)Nb * K * L * 4);
    float* Queries = (float*)alloc((size_t)Nb * K * L * 4);
    float* Values  = (float*)alloc((size_t)Nb * V * L * 4);
    bf16*  Ybf     = (bf16*)alloc((size_t)Nb * LD * 2);
    float* ctx     = (float*)alloc((size_t)Nb * H * 96 * 48 * 4);
    bf16* Wk_bf = (bf16*)alloc((size_t)K * D * 2);
    bf16* Wq_bf = (bf16*)alloc((size_t)K * D * 2);
    bf16* Wv_bf = (bf16*)alloc((size_t)V * D * 2);
    bf16* Wr_bf = (bf16*)alloc((size_t)D * V * 2);
    bf16* W1_bf = (bf16*)alloc((size_t)M * D * 2);
    bf16* W2_bf = (bf16*)alloc((size_t)D * M * 2);
    // reuse regions (lifetimes disjoint):
    bf16* Hbf   = (bf16*)Keys;    // [50176,3072] bf16 == Keys+Queries region exactly
    bf16* Y2bf  = (bf16*)Values;  // [N, L*D] bf16 fits Values' 77MB exactly
    bf16* attbf = (bf16*)Ybf;     // [N, 384*L] bf16 fits Ybf's 77MB
    float* x1   = (float*)d_out;  // post-attention residual lives in d_out

    auto castw = [&](const float* s, bf16* dp, int n) {
        cast_kernel<<<(n + 255) / 256, 256, 0, stream>>>(s, dp, n);
    };
    castw(Wk, Wk_bf, K * D);
    castw(Wq, Wq_bf, K * D);
    castw(Wv, Wv_bf, V * D);
    castw(Wr, Wr_bf, D * V);
    castw(W1, W1_bf, M * D);
    castw(W2, W2_bf, D * M);

    // LN1: x -> Ybf (flat; viewed per batch as [768,3136] row-major)
    ln_kernel<<<Nb * L, 256, 0, stream>>>(x, ln1_g, ln1_b, Ybf);

    dim3 blk(256);
    // projections: C[768|384, 3136] = W @ Xf, per batch
    gemm_kernel<0, false><<<dim3(25, 6, 16), blk, 0, stream>>>(
        Wk_bf, Ybf, bk, nullptr, Keys, 768, 3136, 768, (long)LD, (long)K * L, 0);
    gemm_kernel<0, false><<<dim3(25, 6, 16), blk, 0, stream>>>(
        Wq_bf, Ybf, bq, nullptr, Queries, 768, 3136, 768, (long)LD, (long)K * L, 0);
    gemm_kernel<0, false><<<dim3(25, 3, 16), blk, 0, stream>>>(
        Wv_bf, Ybf, bv, nullptr, Values, 384, 3136, 768, (long)LD, (long)V * L, 0);

    softmax_rows<<<Nb * K, 256, 0, stream>>>(Keys);             // kh (in place)
    softmax_q<<<dim3(13, Nb * H), 256, 0, stream>>>(Queries);   // qh (in place)

    hipMemsetAsync(ctx, 0, (size_t)Nb * H * 96 * 48 * 4, stream);
    context_kernel<<<dim3(2, Nb * H), 256, 0, stream>>>(Keys, Values, ctx);
    att_kernel<<<dim3(13, Nb * H), 256, 0, stream>>>(ctx, Queries, attbf);

    // Wr projection + residual (flat add) -> x1 (in d_out)
    gemm_kernel<1, false><<<dim3(25, 6, 16), blk, 0, stream>>>(
        Wr_bf, attbf, br, x, x1, 768, 3136, 384, (long)V * L, (long)LD, (long)LD);

    // LN2: x1 -> Y2bf ([50176, 768] rows)
    ln_kernel<<<Nb * L, 256, 0, stream>>>(x1, ln2_g, ln2_b, Y2bf);

    // MLP1: [50176,3072] = Y2 @ W1^T, +b1, gelu, bf16
    gemm_kernel<2, true><<<dim3(24, 392, 1), blk, 0, stream>>>(
        Y2bf, W1_bf, b1, nullptr, Hbf, 50176, 3072, 768, 0, 0, 0);
    // MLP2: d_out = H @ W2^T + b2 + x1
    gemm_kernel<3, true><<<dim3(6, 392, 1), blk, 0, stream>>>(
        Hbf, W2_bf, b2, x1, d_out, 50176, 768, 3072, 0, 0, 0);
}

// Round 2
// 1768.239 us; speedup vs baseline: 1.4207x; 1.4207x over previous
//
#include <hip/hip_runtime.h>
#include <hip/hip_bf16.h>

using bf16 = __hip_bfloat16;
typedef __attribute__((ext_vector_type(8))) short short8;
typedef __attribute__((ext_vector_type(4))) float f32x4;

__device__ __forceinline__ float bfbits2f(unsigned short h) {
    unsigned v = (unsigned)h << 16;
    return __uint_as_float(v);
}

__device__ __forceinline__ void gload16(const void* g, void* l) {
    __builtin_amdgcn_global_load_lds(
        (const __attribute__((address_space(1))) unsigned int*)g,
        (__attribute__((address_space(3))) unsigned int*)l, 16, 0, 0);
}

__device__ __forceinline__ float gelu_exact(float v) {
    return 0.5f * v * (1.0f + erff(v * 0.70710678118654752f));
}

// ---- block reduce helpers (256 threads = 4 waves) ----
__device__ __forceinline__ float blk_sum(float v, float* red) {
#pragma unroll
    for (int o = 32; o > 0; o >>= 1) v += __shfl_down(v, o, 64);
    int wv = threadIdx.x >> 6;
    __syncthreads();
    if ((threadIdx.x & 63) == 0) red[wv] = v;
    __syncthreads();
    return red[0] + red[1] + red[2] + red[3];
}

// ---- LayerNorm over D=768, one block per (n,l) row, f32 in -> bf16 out ----
__global__ __launch_bounds__(256) void ln_kernel(const float* __restrict__ x,
                                                 const float* __restrict__ g,
                                                 const float* __restrict__ b,
                                                 bf16* __restrict__ y) {
    __shared__ float red[4];
    size_t base = (size_t)blockIdx.x * 768;
    int t = threadIdx.x;
    float v0 = x[base + t], v1 = x[base + t + 256], v2 = x[base + t + 512];
    float s = blk_sum(v0 + v1 + v2, red);
    float mean = s * (1.0f / 768.0f);
    float d0 = v0 - mean, d1 = v1 - mean, d2 = v2 - mean;
    float sq = blk_sum(d0 * d0 + d1 * d1 + d2 * d2, red);
    float rstd = rsqrtf(sq * (1.0f / 768.0f) + 1e-6f);
    y[base + t]       = __float2bfloat16(d0 * rstd * g[t]       + b[t]);
    y[base + t + 256] = __float2bfloat16(d1 * rstd * g[t + 256] + b[t + 256]);
    y[base + t + 512] = __float2bfloat16(d2 * rstd * g[t + 512] + b[t + 512]);
}

// ---- f32 -> bf16 cast ----
__global__ __launch_bounds__(256) void cast_kernel(const float* __restrict__ s,
                                                   bf16* __restrict__ d, int n) {
    int i = blockIdx.x * 256 + threadIdx.x;
    if (i < n) d[i] = __float2bfloat16(s[i]);
}

// ---- bf16 transpose per batch: Y [768,3136] -> Xt [3136,768] ----
__global__ __launch_bounds__(256) void transp_k(const bf16* __restrict__ Y,
                                                bf16* __restrict__ Xt) {
    __shared__ unsigned short tile[64][65];
    const size_t LD = (size_t)768 * 3136;
    int n = blockIdx.z;
    int l0 = blockIdx.x * 64, d0 = blockIdx.y * 64;
    const unsigned short* Yp = (const unsigned short*)Y + (size_t)n * LD;
    unsigned short* Xp = (unsigned short*)Xt + (size_t)n * LD;
    int t = threadIdx.x;
#pragma unroll
    for (int j = 0; j < 2; j++) {
        int e = t + 256 * j;
        int dd = e >> 3, lg = (e & 7) * 8;
        short8 v = *(const short8*)&Yp[(size_t)(d0 + dd) * 3136 + l0 + lg];
#pragma unroll
        for (int u = 0; u < 8; u++) tile[dd][lg + u] = (unsigned short)v[u];
    }
    __syncthreads();
#pragma unroll
    for (int j = 0; j < 2; j++) {
        int e = t + 256 * j;
        int ll = e >> 3, dg = (e & 7) * 8;
        short8 v;
#pragma unroll
        for (int u = 0; u < 8; u++) v[u] = (short)tile[dg + u][ll];
        *(short8*)&Xp[(size_t)(l0 + ll) * 768 + d0 + dg] = v;
    }
}

// ---- GEMM: C[M,N] = A[M,K] * B[N,K]^T (+epilogue). 128x128 tile, BK=64 ----
// global_load_lds staging, XOR-swizzled slots, XCD-chunked block swizzle.
// MODE 0: C=bf16, v + bias[col]
// MODE 1: C=f32,  v + bias[row] + resid[flat]
// MODE 2: C=bf16, gelu(v + bias[col])
// MODE 3: C=f32,  v + bias[col] + resid[flat]
template <int MODE>
__global__ __launch_bounds__(256) void gemm_nk(
    const bf16* __restrict__ A, const bf16* __restrict__ B,
    const float* __restrict__ bias, const float* __restrict__ resid,
    void* __restrict__ Cv, int M, int N, int K, long sB, long sC, long sR) {
    __shared__ bf16 As[128 * 64];
    __shared__ bf16 Bs[128 * 64];
    const int tid = threadIdx.x;
    const int lane = tid & 63, wave = tid >> 6;

    // XCD-chunked bijective swizzle; bn varies fastest within a chunk
    const int nbn = gridDim.x;
    const int nwg = nbn * gridDim.y;
    const int orig = blockIdx.y * nbn + blockIdx.x;
    const int qq = nwg >> 3, rm = nwg & 7;
    const int xcd = orig & 7, pos = orig >> 3;
    const int work = (xcd < rm ? xcd * (qq + 1) : rm * (qq + 1) + (xcd - rm) * qq) + pos;
    const int bn = work % nbn, bm = work / nbn;
    const int bz = blockIdx.z;

    const int wm = (wave >> 1) * 64, wn = (wave & 1) * 64;
    const int frow = lane & 15, fsb = lane >> 4;
    const int fxr = frow & 7;

    // staging: per-lane pre-swizzled global source; linear wave-uniform LDS dest
    const int srow = lane >> 3;           // row within 8-row chunk
    const int sslot = (lane & 7) ^ srow;  // inverse-swizzled 16B slot
    const size_t rowB = (size_t)K * 2;
    const char* Ap = (const char*)A +
        ((size_t)bm * 128 + wave * 32 + srow) * rowB + (size_t)sslot * 16;
    const char* Bp = (const char*)(B + (size_t)bz * sB) +
        ((size_t)bn * 128 + wave * 32 + srow) * rowB + (size_t)sslot * 16;

    f32x4 acc[4][4];
#pragma unroll
    for (int mi = 0; mi < 4; mi++)
#pragma unroll
        for (int ni = 0; ni < 4; ni++)
#pragma unroll
            for (int r = 0; r < 4; r++) acc[mi][ni][r] = 0.0f;

    for (int kt = 0; kt < K; kt += 64) {
#pragma unroll
        for (int c = 0; c < 4; c++) {
            gload16(Ap + (size_t)c * 8 * rowB + (size_t)kt * 2, &As[(wave * 4 + c) * 512]);
            gload16(Bp + (size_t)c * 8 * rowB + (size_t)kt * 2, &Bs[(wave * 4 + c) * 512]);
        }
        __syncthreads();   // drains vmcnt: staged data visible
#pragma unroll
        for (int k2 = 0; k2 < 2; k2++) {
            short8 af[4], bfv[4];
#pragma unroll
            for (int mi = 0; mi < 4; mi++) {
                int r = wm + mi * 16 + frow;
                af[mi] = *(const short8*)&As[r * 64 + (((k2 * 4 + fsb) ^ fxr) << 3)];
            }
#pragma unroll
            for (int ni = 0; ni < 4; ni++) {
                int r = wn + ni * 16 + frow;
                bfv[ni] = *(const short8*)&Bs[r * 64 + (((k2 * 4 + fsb) ^ fxr) << 3)];
            }
#pragma unroll
            for (int mi = 0; mi < 4; mi++)
#pragma unroll
                for (int ni = 0; ni < 4; ni++)
                    acc[mi][ni] = __builtin_amdgcn_mfma_f32_16x16x32_bf16(
                        af[mi], bfv[ni], acc[mi][ni], 0, 0, 0);
        }
        __syncthreads();   // protect LDS before next-iter staging
    }

    float* Cf = (float*)Cv + (size_t)bz * sC;
    bf16* Cb = (bf16*)Cv + (size_t)bz * sC;
    const float* Rp = resid ? (resid + (size_t)bz * sR) : nullptr;
#pragma unroll
    for (int mi = 0; mi < 4; mi++)
#pragma unroll
        for (int ni = 0; ni < 4; ni++)
#pragma unroll
            for (int r = 0; r < 4; r++) {
                int row = bm * 128 + wm + mi * 16 + (fsb << 2) + r;
                int col = bn * 128 + wn + ni * 16 + frow;
                if (col < N) {
                    float v = acc[mi][ni][r];
                    size_t idx = (size_t)row * N + col;
                    if (MODE == 0) Cb[idx] = __float2bfloat16(v + bias[col]);
                    else if (MODE == 1) Cf[idx] = v + bias[row] + Rp[idx];
                    else if (MODE == 2) Cb[idx] = __float2bfloat16(gelu_exact(v + bias[col]));
                    else Cf[idx] = v + bias[col] + Rp[idx];
                }
            }
}

// ---- keys spatial softmax (over l), transposed layout Kt [n*3136, 768] ----
// pass 1: per l-chunk partial max / expsum per channel
__global__ __launch_bounds__(256) void softk_part(const bf16* __restrict__ Kt,
                                                  float* __restrict__ pm,
                                                  float* __restrict__ ps) {
    int g = blockIdx.y;               // 0..47 : n = g/3, cgroup = g%3
    int lc = blockIdx.x;              // 0..7
    int n = g / 3;
    int c = (g % 3) * 256 + threadIdx.x;
    const unsigned short* base = (const unsigned short*)Kt +
        ((size_t)n * 3136 + (size_t)lc * 392) * 768 + c;
    float mx = -1e30f;
    for (int l = 0; l < 392; l++) mx = fmaxf(mx, bfbits2f(base[(size_t)l * 768]));
    float s = 0.f;
    for (int l = 0; l < 392; l++) s += expf(bfbits2f(base[(size_t)l * 768]) - mx);
    int idx = g * 256 + threadIdx.x;
    pm[(size_t)lc * 12288 + idx] = mx;
    ps[(size_t)lc * 12288 + idx] = s;
}
// pass 2: combine partials, normalize chunk in place (bf16 out)
__global__ __launch_bounds__(256) void softk_fin(bf16* __restrict__ Kt,
                                                 const float* __restrict__ pm,
                                                 const float* __restrict__ ps) {
    int g = blockIdx.y;
    int lc = blockIdx.x;
    int n = g / 3;
    int c = (g % 3) * 256 + threadIdx.x;
    int idx = g * 256 + threadIdx.x;
    float M = -1e30f;
#pragma unroll
    for (int i = 0; i < 8; i++) M = fmaxf(M, pm[(size_t)i * 12288 + idx]);
    float S = 0.f;
#pragma unroll
    for (int i = 0; i < 8; i++)
        S += ps[(size_t)i * 12288 + idx] * expf(pm[(size_t)i * 12288 + idx] - M);
    float inv = 1.0f / S;
    unsigned short* base = (unsigned short*)Kt + ((size_t)n * 3136 + (size_t)lc * 392) * 768 + c;
    for (int l = 0; l < 392; l++) {
        float e = expf(bfbits2f(base[(size_t)l * 768]) - M) * inv;
        ((bf16*)base)[(size_t)l * 768] = __float2bfloat16(e);
    }
}

// ---- queries channel softmax: 96 contiguous channels per (token, head) ----
__global__ __launch_bounds__(256) void softq_k(bf16* __restrict__ Qt) {
    int u = blockIdx.x * 256 + threadIdx.x;   // (token, head); 401408 total
    unsigned short* p = (unsigned short*)Qt + (size_t)(u >> 3) * 768 + (size_t)(u & 7) * 96;
    float v[96];
#pragma unroll
    for (int j = 0; j < 12; j++) {
        short8 w = *(const short8*)&p[j * 8];
#pragma unroll
        for (int x = 0; x < 8; x++) v[j * 8 + x] = bfbits2f((unsigned short)w[x]);
    }
    float mx = -1e30f;
#pragma unroll
    for (int i = 0; i < 96; i++) mx = fmaxf(mx, v[i]);
    float s = 0.f;
#pragma unroll
    for (int i = 0; i < 96; i++) { v[i] = expf(v[i] - mx); s += v[i]; }
    float inv = 1.0f / s;
#pragma unroll
    for (int j = 0; j < 12; j++) {
        short8 w;
#pragma unroll
        for (int x = 0; x < 8; x++)
            w[x] = (short)__bfloat16_as_ushort(__float2bfloat16(v[j * 8 + x] * inv));
        *(short8*)&p[j * 8] = w;
    }
}

// ---- context[nh,96,48] += sum_l kh[l,96]*vh[l,48], transposed bf16 in ----
__global__ __launch_bounds__(256) void context_k(const bf16* __restrict__ Kt,
                                                 const bf16* __restrict__ Vt,
                                                 float* __restrict__ ctx) {
    __shared__ float ks[32][96];
    __shared__ float vs[32][48];
    int nh = blockIdx.y;
    int n = nh >> 3, h = nh & 7;
    int t = threadIdx.x;
    const unsigned short* kp = (const unsigned short*)Kt;
    const unsigned short* vp = (const unsigned short*)Vt;
    int a = t >> 4, bq = t & 15;      // kk = a*6+i, vv = bq*3+j
    float acc[6][3];
#pragma unroll
    for (int i = 0; i < 6; i++)
#pragma unroll
        for (int j = 0; j < 3; j++) acc[i][j] = 0.f;
    int l0 = blockIdx.x * 448;
    for (int ls = l0; ls < l0 + 448; ls += 32) {
        __syncthreads();
#pragma unroll
        for (int j = 0; j < 6; j++) {
            int e = t + 256 * j;
            int row = e / 48, cp = e % 48;
            unsigned u = *(const unsigned*)&kp[((size_t)(n * 3136 + ls + row)) * 768 + h * 96 + cp * 2];
            ks[row][cp * 2] = bfbits2f((unsigned short)(u & 0xffff));
            ks[row][cp * 2 + 1] = bfbits2f((unsigned short)(u >> 16));
        }
#pragma unroll
        for (int j = 0; j < 3; j++) {
            int e = t + 256 * j;
            int row = e / 24, cp = e % 24;
            unsigned u = *(const unsigned*)&vp[((size_t)(n * 3136 + ls + row)) * 384 + h * 48 + cp * 2];
            vs[row][cp * 2] = bfbits2f((unsigned short)(u & 0xffff));
            vs[row][cp * 2 + 1] = bfbits2f((unsigned short)(u >> 16));
        }
        __syncthreads();
        for (int ll = 0; ll < 32; ll++) {
            float kv[6], vv[3];
#pragma unroll
            for (int i = 0; i < 6; i++) kv[i] = ks[ll][a * 6 + i];
#pragma unroll
            for (int j = 0; j < 3; j++) vv[j] = vs[ll][bq * 3 + j];
#pragma unroll
            for (int i = 0; i < 6; i++)
#pragma unroll
                for (int j = 0; j < 3; j++) acc[i][j] += kv[i] * vv[j];
        }
    }
    float* cb = ctx + (size_t)nh * 4608;
#pragma unroll
    for (int i = 0; i < 6; i++)
#pragma unroll
        for (int j = 0; j < 3; j++)
            atomicAdd(&cb[(a * 6 + i) * 48 + bq * 3 + j], acc[i][j]);
}

// ---- att_t[token,48-slice] = qh[token,96] @ ctx[96,48], bf16 out ----
__global__ __launch_bounds__(256) void att_k(const float* __restrict__ ctx,
                                             const bf16* __restrict__ Qt,
                                             bf16* __restrict__ att) {
    __shared__ float cs[4608];
    int nh = blockIdx.y;
    int n = nh >> 3, h = nh & 7;
    for (int j = threadIdx.x; j < 4608; j += 256) cs[j] = ctx[(size_t)nh * 4608 + j];
    __syncthreads();
    int l = blockIdx.x * 256 + threadIdx.x;
    if (l >= 3136) return;
    const unsigned short* qp = (const unsigned short*)Qt + ((size_t)(n * 3136 + l)) * 768 + h * 96;
    float qv[96];
#pragma unroll
    for (int j = 0; j < 12; j++) {
        short8 w = *(const short8*)&qp[j * 8];
#pragma unroll
        for (int x = 0; x < 8; x++) qv[j * 8 + x] = bfbits2f((unsigned short)w[x]);
    }
    unsigned short ov[48];
#pragma unroll
    for (int vb = 0; vb < 12; vb++) {
        f32x4 s;
        s[0] = s[1] = s[2] = s[3] = 0.f;
        for (int k = 0; k < 96; k++) {
            f32x4 c4 = *(const f32x4*)&cs[k * 48 + vb * 4];
            float q = qv[k];
#pragma unroll
            for (int x = 0; x < 4; x++) s[x] += c4[x] * q;
        }
#pragma unroll
        for (int x = 0; x < 4; x++)
            ov[vb * 4 + x] = __bfloat16_as_ushort(__float2bfloat16(s[x]));
    }
    unsigned short* op = (unsigned short*)att + ((size_t)n * 3200 + l) * 384 + h * 48;
#pragma unroll
    for (int j = 0; j < 6; j++) *(short8*)&op[j * 8] = *(short8*)&ov[j * 8];
}

extern "C" void kernel_launch(void* const* d_in, const int* in_sizes, int n_in,
                              void* d_out, int out_size, void* d_ws, size_t ws_size,
                              hipStream_t stream) {
    (void)in_sizes; (void)n_in; (void)out_size; (void)ws_size;
    const float* x     = (const float*)d_in[0];
    const float* ln1_g = (const float*)d_in[1];
    const float* ln1_b = (const float*)d_in[2];
    const float* Wk    = (const float*)d_in[3];
    const float* bk    = (const float*)d_in[4];
    const float* Wq    = (const float*)d_in[5];
    const float* bq    = (const float*)d_in[6];
    const float* Wv    = (const float*)d_in[7];
    const float* bv    = (const float*)d_in[8];
    const float* Wr    = (const float*)d_in[9];
    const float* br    = (const float*)d_in[10];
    const float* ln2_g = (const float*)d_in[11];
    const float* ln2_b = (const float*)d_in[12];
    const float* W1    = (const float*)d_in[13];
    const float* b1    = (const float*)d_in[14];
    const float* W2    = (const float*)d_in[15];
    const float* b2    = (const float*)d_in[16];

    const int Nb = 16, L = 3136, D = 768, V = 384, M = 3072;
    const size_t LD = (size_t)L * D;
    const size_t sz77 = (size_t)50176 * 768 * 2;

    char* w = (char*)d_ws;
    size_t off = 0;
    auto alloc = [&](size_t bytes) {
        char* p = w + off;
        off = (off + bytes + 255) & ~(size_t)255;
        return p;
    };
    bf16* Ybf  = (bf16*)alloc(sz77);                       // also Hbf[0..]
    bf16* Xt   = (bf16*)alloc(sz77);
    bf16* Kt   = (bf16*)alloc(sz77);
    bf16* Qt   = (bf16*)alloc(sz77);
    bf16* Vt   = (bf16*)alloc((size_t)50176 * 384 * 2);    // also Y2bf[0..]
    bf16* attb = (bf16*)alloc((size_t)16 * 3200 * 384 * 2);
    float* ctx = (float*)alloc((size_t)128 * 4608 * 4);
    float* pm  = (float*)alloc((size_t)8 * 12288 * 4);
    float* ps  = (float*)alloc((size_t)8 * 12288 * 4);
    bf16* Wk_bf = (bf16*)alloc((size_t)768 * 768 * 2);
    bf16* Wq_bf = (bf16*)alloc((size_t)768 * 768 * 2);
    bf16* Wv_bf = (bf16*)alloc((size_t)384 * 768 * 2);
    bf16* Wr_bf = (bf16*)alloc((size_t)768 * 384 * 2);
    bf16* W1_bf = (bf16*)alloc((size_t)3072 * 768 * 2);
    bf16* W2_bf = (bf16*)alloc((size_t)768 * 3072 * 2);
    bf16* Hbf  = Ybf;    // [50176,3072] = 4 x sz77 contiguous
    bf16* Y2bf = Vt;     // [50176,768] fits Vt+attb region
    float* x1  = (float*)d_out;

    auto castw = [&](const float* s, bf16* dp, int n) {
        cast_kernel<<<(n + 255) / 256, 256, 0, stream>>>(s, dp, n);
    };
    castw(Wk, Wk_bf, 768 * 768);
    castw(Wq, Wq_bf, 768 * 768);
    castw(Wv, Wv_bf, 384 * 768);
    castw(Wr, Wr_bf, 768 * 384);
    castw(W1, W1_bf, 3072 * 768);
    castw(W2, W2_bf, 768 * 3072);

    // LN1: x -> Ybf (flat [n][d'][l'] view), then transpose -> Xt [n*3136, 768]
    ln_kernel<<<Nb * L, 256, 0, stream>>>(x, ln1_g, ln1_b, Ybf);
    transp_k<<<dim3(49, 12, 16), 256, 0, stream>>>(Ybf, Xt);

    dim3 blk(256);
    // projections: [50176,768] @ [out,768]^T
    gemm_nk<0><<<dim3(6, 392, 1), blk, 0, stream>>>(Xt, Wk_bf, bk, nullptr, Kt,
                                                    50176, 768, 768, 0, 0, 0);
    gemm_nk<0><<<dim3(6, 392, 1), blk, 0, stream>>>(Xt, Wq_bf, bq, nullptr, Qt,
                                                    50176, 768, 768, 0, 0, 0);
    gemm_nk<0><<<dim3(3, 392, 1), blk, 0, stream>>>(Xt, Wv_bf, bv, nullptr, Vt,
                                                    50176, 384, 768, 0, 0, 0);

    softk_part<<<dim3(8, 48), blk, 0, stream>>>(Kt, pm, ps);
    softk_fin<<<dim3(8, 48), blk, 0, stream>>>(Kt, pm, ps);
    softq_k<<<1568, blk, 0, stream>>>(Qt);

    hipMemsetAsync(ctx, 0, (size_t)128 * 4608 * 4, stream);
    context_k<<<dim3(7, 128), blk, 0, stream>>>(Kt, Vt, ctx);
    att_k<<<dim3(13, 128), blk, 0, stream>>>(ctx, Qt, attb);

    // Wr projection + residual: C[768,3136] per batch (flat [D,L] layout) -> d_out
    gemm_nk<1><<<dim3(25, 6, 16), blk, 0, stream>>>(Wr_bf, attb, br, x, x1,
                                                    768, 3136, 384,
                                                    (long)3200 * 384, (long)LD, (long)LD);

    // LN2: x1 -> Y2bf
    ln_kernel<<<Nb * L, 256, 0, stream>>>(x1, ln2_g, ln2_b, Y2bf);

    // MLP1: [50176,3072] = Y2 @ W1^T, +b1, gelu, bf16
    gemm_nk<2><<<dim3(24, 392, 1), blk, 0, stream>>>(Y2bf, W1_bf, b1, nullptr, Hbf,
                                                     50176, 3072, 768, 0, 0, 0);
    // MLP2: d_out = H @ W2^T + b2 + x1
    gemm_nk<3><<<dim3(6, 392, 1), blk, 0, stream>>>(Hbf, W2_bf, b2, x1, d_out,
                                                    50176, 768, 3072, 0, 0, 0);
}

// Round 3
// 1614.979 us; speedup vs baseline: 1.5556x; 1.0949x over previous
//
#include <hip/hip_runtime.h>
#include <hip/hip_bf16.h>

using bf16 = __hip_bfloat16;
typedef __attribute__((ext_vector_type(8))) short short8;
typedef __attribute__((ext_vector_type(4))) short short4v;
typedef __attribute__((ext_vector_type(4))) float f32x4;

__device__ __forceinline__ float bfbits2f(unsigned short h) {
    unsigned v = (unsigned)h << 16;
    return __uint_as_float(v);
}

__device__ __forceinline__ void gload16(const void* g, void* l) {
    __builtin_amdgcn_global_load_lds(
        (const __attribute__((address_space(1))) unsigned int*)g,
        (__attribute__((address_space(3))) unsigned int*)l, 16, 0, 0);
}

// tanh-form GELU: x - x/(exp(2*0.79788456*x*(1+0.044715 x^2)) + 1)
// 1 v_exp + 1 v_rcp + ~6 VALU; |diff vs exact erf-GELU| <= ~3e-3
__device__ __forceinline__ float gelu_fast(float x) {
    float x2 = x * x;
    float u = x * __builtin_fmaf(0.07135481f, x2, 1.59576912f);
    float e = __expf(u);
    return x - x * __builtin_amdgcn_rcpf(e + 1.0f);
}

// ---- block reduce over 3 waves (192 threads) ----
__device__ __forceinline__ float blk_sum3(float v, float* red) {
#pragma unroll
    for (int o = 32; o > 0; o >>= 1) v += __shfl_down(v, o, 64);
    int wv = threadIdx.x >> 6;
    __syncthreads();
    if ((threadIdx.x & 63) == 0) red[wv] = v;
    __syncthreads();
    return red[0] + red[1] + red[2];
}

// ---- LayerNorm over D=768, one block per row, f32 in -> bf16 out ----
__global__ __launch_bounds__(192) void ln_f32(const float* __restrict__ x,
                                              const float* __restrict__ g,
                                              const float* __restrict__ b,
                                              bf16* __restrict__ y) {
    __shared__ float red[3];
    size_t base = (size_t)blockIdx.x * 768;
    int t = threadIdx.x;
    float4 v = *(const float4*)&x[base + t * 4];
    float s = blk_sum3(v.x + v.y + v.z + v.w, red);
    float mean = s * (1.0f / 768.0f);
    float d0 = v.x - mean, d1 = v.y - mean, d2 = v.z - mean, d3 = v.w - mean;
    float sq = blk_sum3(d0 * d0 + d1 * d1 + d2 * d2 + d3 * d3, red);
    float rstd = rsqrtf(sq * (1.0f / 768.0f) + 1e-6f);
    float4 gv = *(const float4*)&g[t * 4];
    float4 bv = *(const float4*)&b[t * 4];
    short4v o;
    o[0] = (short)__bfloat16_as_ushort(__float2bfloat16(d0 * rstd * gv.x + bv.x));
    o[1] = (short)__bfloat16_as_ushort(__float2bfloat16(d1 * rstd * gv.y + bv.y));
    o[2] = (short)__bfloat16_as_ushort(__float2bfloat16(d2 * rstd * gv.z + bv.z));
    o[3] = (short)__bfloat16_as_ushort(__float2bfloat16(d3 * rstd * gv.w + bv.w));
    *(short4v*)&((unsigned short*)y)[base + t * 4] = o;
}

// ---- LayerNorm, bf16 in -> bf16 out ----
__global__ __launch_bounds__(192) void ln_bf(const bf16* __restrict__ x,
                                             const float* __restrict__ g,
                                             const float* __restrict__ b,
                                             bf16* __restrict__ y) {
    __shared__ float red[3];
    size_t base = (size_t)blockIdx.x * 768;
    int t = threadIdx.x;
    short4v w = *(const short4v*)&((const unsigned short*)x)[base + t * 4];
    float v0 = bfbits2f((unsigned short)w[0]), v1 = bfbits2f((unsigned short)w[1]);
    float v2 = bfbits2f((unsigned short)w[2]), v3 = bfbits2f((unsigned short)w[3]);
    float s = blk_sum3(v0 + v1 + v2 + v3, red);
    float mean = s * (1.0f / 768.0f);
    float d0 = v0 - mean, d1 = v1 - mean, d2 = v2 - mean, d3 = v3 - mean;
    float sq = blk_sum3(d0 * d0 + d1 * d1 + d2 * d2 + d3 * d3, red);
    float rstd = rsqrtf(sq * (1.0f / 768.0f) + 1e-6f);
    float4 gv = *(const float4*)&g[t * 4];
    float4 bv = *(const float4*)&b[t * 4];
    short4v o;
    o[0] = (short)__bfloat16_as_ushort(__float2bfloat16(d0 * rstd * gv.x + bv.x));
    o[1] = (short)__bfloat16_as_ushort(__float2bfloat16(d1 * rstd * gv.y + bv.y));
    o[2] = (short)__bfloat16_as_ushort(__float2bfloat16(d2 * rstd * gv.z + bv.z));
    o[3] = (short)__bfloat16_as_ushort(__float2bfloat16(d3 * rstd * gv.w + bv.w));
    *(short4v*)&((unsigned short*)y)[base + t * 4] = o;
}

// ---- f32 -> bf16 cast ----
__global__ __launch_bounds__(256) void cast_kernel(const float* __restrict__ s,
                                                   bf16* __restrict__ d, int n) {
    int i = blockIdx.x * 256 + threadIdx.x;
    if (i < n) d[i] = __float2bfloat16(s[i]);
}

// ---- concat K/Q/V biases into one [1920] f32 buffer ----
__global__ __launch_bounds__(256) void bias_cat(const float* __restrict__ bk,
                                                const float* __restrict__ bq,
                                                const float* __restrict__ bv,
                                                float* __restrict__ o) {
    int i = blockIdx.x * 256 + threadIdx.x;
    if (i < 768) o[i] = bk[i];
    else if (i < 1536) o[i] = bq[i - 768];
    else if (i < 1920) o[i] = bv[i - 1536];
}

// ---- bf16 transpose per batch: Y [768,3136] -> Xt [3136,768] ----
__global__ __launch_bounds__(256) void transp_k(const bf16* __restrict__ Y,
                                                bf16* __restrict__ Xt) {
    __shared__ unsigned short tile[64][65];
    const size_t LD = (size_t)768 * 3136;
    int n = blockIdx.z;
    int l0 = blockIdx.x * 64, d0 = blockIdx.y * 64;
    const unsigned short* Yp = (const unsigned short*)Y + (size_t)n * LD;
    unsigned short* Xp = (unsigned short*)Xt + (size_t)n * LD;
    int t = threadIdx.x;
#pragma unroll
    for (int j = 0; j < 2; j++) {
        int e = t + 256 * j;
        int dd = e >> 3, lg = (e & 7) * 8;
        short8 v = *(const short8*)&Yp[(size_t)(d0 + dd) * 3136 + l0 + lg];
#pragma unroll
        for (int u = 0; u < 8; u++) tile[dd][lg + u] = (unsigned short)v[u];
    }
    __syncthreads();
#pragma unroll
    for (int j = 0; j < 2; j++) {
        int e = t + 256 * j;
        int ll = e >> 3, dg = (e & 7) * 8;
        short8 v;
#pragma unroll
        for (int u = 0; u < 8; u++) v[u] = (short)tile[dg + u][ll];
        *(short8*)&Xp[(size_t)(l0 + ll) * 768 + d0 + dg] = v;
    }
}

// ---- GEMM: C[M,N] = A[M,K] * B[N,K]^T (+epilogue). 128x128 tile, BK=64 ----
// MODE 0: split-KQV bf16: col<768 -> C0[row*768+col]; <1536 -> C1; else C2[row*384+..]; +bias[col]
// MODE 1: C0=bf16, v + bias[row] + residf[flat]
// MODE 2: C0=bf16, gelu(v + bias[col])
// MODE 3: C0=f32,  v + bias[col] + residb(bf16)[flat]
template <int MODE>
__global__ __launch_bounds__(256) void gemm_nk(
    const bf16* __restrict__ A, const bf16* __restrict__ B,
    const float* __restrict__ bias, const void* __restrict__ resid,
    void* __restrict__ C0, void* __restrict__ C1, void* __restrict__ C2,
    int M, int N, int K, long sB, long sC, long sR) {
    __shared__ bf16 As[128 * 64];
    __shared__ bf16 Bs[128 * 64];
    const int tid = threadIdx.x;
    const int lane = tid & 63, wave = tid >> 6;

    // XCD-chunked bijective swizzle; bn varies fastest within a chunk
    const int nbn = gridDim.x;
    const int nwg = nbn * gridDim.y;
    const int orig = blockIdx.y * nbn + blockIdx.x;
    const int qq = nwg >> 3, rm = nwg & 7;
    const int xcd = orig & 7, pos = orig >> 3;
    const int work = (xcd < rm ? xcd * (qq + 1) : rm * (qq + 1) + (xcd - rm) * qq) + pos;
    const int bn = work % nbn, bm = work / nbn;
    const int bz = blockIdx.z;

    const int wm = (wave >> 1) * 64, wn = (wave & 1) * 64;
    const int frow = lane & 15, fsb = lane >> 4;
    const int fxr = frow & 7;

    // staging: per-lane pre-swizzled global source; linear wave-uniform LDS dest
    const int srow = lane >> 3;           // row within 8-row chunk
    const int sslot = (lane & 7) ^ srow;  // inverse-swizzled 16B slot
    const size_t rowB = (size_t)K * 2;
    const char* Ap = (const char*)A +
        ((size_t)bm * 128 + wave * 32 + srow) * rowB + (size_t)sslot * 16;
    const char* Bp = (const char*)(B + (size_t)bz * sB) +
        ((size_t)bn * 128 + wave * 32 + srow) * rowB + (size_t)sslot * 16;

    f32x4 acc[4][4];
#pragma unroll
    for (int mi = 0; mi < 4; mi++)
#pragma unroll
        for (int ni = 0; ni < 4; ni++)
#pragma unroll
            for (int r = 0; r < 4; r++) acc[mi][ni][r] = 0.0f;

    for (int kt = 0; kt < K; kt += 64) {
#pragma unroll
        for (int c = 0; c < 4; c++) {
            gload16(Ap + (size_t)c * 8 * rowB + (size_t)kt * 2, &As[(wave * 4 + c) * 512]);
            gload16(Bp + (size_t)c * 8 * rowB + (size_t)kt * 2, &Bs[(wave * 4 + c) * 512]);
        }
        __syncthreads();   // drains vmcnt: staged data visible
#pragma unroll
        for (int k2 = 0; k2 < 2; k2++) {
            short8 af[4], bfv[4];
#pragma unroll
            for (int mi = 0; mi < 4; mi++) {
                int r = wm + mi * 16 + frow;
                af[mi] = *(const short8*)&As[r * 64 + (((k2 * 4 + fsb) ^ fxr) << 3)];
            }
#pragma unroll
            for (int ni = 0; ni < 4; ni++) {
                int r = wn + ni * 16 + frow;
                bfv[ni] = *(const short8*)&Bs[r * 64 + (((k2 * 4 + fsb) ^ fxr) << 3)];
            }
#pragma unroll
            for (int mi = 0; mi < 4; mi++)
#pragma unroll
                for (int ni = 0; ni < 4; ni++)
                    acc[mi][ni] = __builtin_amdgcn_mfma_f32_16x16x32_bf16(
                        af[mi], bfv[ni], acc[mi][ni], 0, 0, 0);
        }
        __syncthreads();   // protect LDS before next-iter staging
    }

    const float* Rf = (const float*)resid + (size_t)bz * sR;
    const unsigned short* Rb = (const unsigned short*)resid + (size_t)bz * sR;
#pragma unroll
    for (int mi = 0; mi < 4; mi++)
#pragma unroll
        for (int ni = 0; ni < 4; ni++)
#pragma unroll
            for (int r = 0; r < 4; r++) {
                int row = bm * 128 + wm + mi * 16 + (fsb << 2) + r;
                int col = bn * 128 + wn + ni * 16 + frow;
                if (col < N) {
                    float v = acc[mi][ni][r];
                    size_t idx = (size_t)row * N + col;
                    if (MODE == 0) {
                        float o = v + bias[col];
                        if (col < 768)
                            ((bf16*)C0)[(size_t)row * 768 + col] = __float2bfloat16(o);
                        else if (col < 1536)
                            ((bf16*)C1)[(size_t)row * 768 + col - 768] = __float2bfloat16(o);
                        else
                            ((bf16*)C2)[(size_t)row * 384 + col - 1536] = __float2bfloat16(o);
                    } else if (MODE == 1) {
                        bf16* Cb = (bf16*)C0 + (size_t)bz * sC;
                        Cb[idx] = __float2bfloat16(v + bias[row] + Rf[idx]);
                    } else if (MODE == 2) {
                        ((bf16*)C0)[idx] = __float2bfloat16(gelu_fast(v + bias[col]));
                    } else {
                        ((float*)C0)[idx] = v + bias[col] + bfbits2f(Rb[idx]);
                    }
                }
            }
}

// ---- keys spatial softmax (over l), transposed layout Kt [n*3136, 768] ----
__global__ __launch_bounds__(256) void softk_part(const bf16* __restrict__ Kt,
                                                  float* __restrict__ pm,
                                                  float* __restrict__ ps) {
    int g = blockIdx.y;               // n = g/3, cgroup = g%3
    int lc = blockIdx.x;              // 0..7
    int n = g / 3;
    int c = (g % 3) * 256 + threadIdx.x;
    const unsigned short* base = (const unsigned short*)Kt +
        ((size_t)n * 3136 + (size_t)lc * 392) * 768 + c;
    float mx = -1e30f;
    for (int l = 0; l < 392; l++) mx = fmaxf(mx, bfbits2f(base[(size_t)l * 768]));
    float s = 0.f;
    for (int l = 0; l < 392; l++) s += expf(bfbits2f(base[(size_t)l * 768]) - mx);
    int idx = g * 256 + threadIdx.x;
    pm[(size_t)lc * 12288 + idx] = mx;
    ps[(size_t)lc * 12288 + idx] = s;
}
__global__ __launch_bounds__(256) void softk_fin(bf16* __restrict__ Kt,
                                                 const float* __restrict__ pm,
                                                 const float* __restrict__ ps) {
    int g = blockIdx.y;
    int lc = blockIdx.x;
    int n = g / 3;
    int c = (g % 3) * 256 + threadIdx.x;
    int idx = g * 256 + threadIdx.x;
    float M = -1e30f;
#pragma unroll
    for (int i = 0; i < 8; i++) M = fmaxf(M, pm[(size_t)i * 12288 + idx]);
    float S = 0.f;
#pragma unroll
    for (int i = 0; i < 8; i++)
        S += ps[(size_t)i * 12288 + idx] * expf(pm[(size_t)i * 12288 + idx] - M);
    float inv = 1.0f / S;
    unsigned short* base = (unsigned short*)Kt + ((size_t)n * 3136 + (size_t)lc * 392) * 768 + c;
    for (int l = 0; l < 392; l++) {
        float e = expf(bfbits2f(base[(size_t)l * 768]) - M) * inv;
        ((bf16*)base)[(size_t)l * 768] = __float2bfloat16(e);
    }
}

// ---- queries channel softmax: 96 contiguous channels per (token, head) ----
__global__ __launch_bounds__(256) void softq_k(bf16* __restrict__ Qt) {
    int u = blockIdx.x * 256 + threadIdx.x;
    unsigned short* p = (unsigned short*)Qt + (size_t)(u >> 3) * 768 + (size_t)(u & 7) * 96;
    float v[96];
#pragma unroll
    for (int j = 0; j < 12; j++) {
        short8 w = *(const short8*)&p[j * 8];
#pragma unroll
        for (int x = 0; x < 8; x++) v[j * 8 + x] = bfbits2f((unsigned short)w[x]);
    }
    float mx = -1e30f;
#pragma unroll
    for (int i = 0; i < 96; i++) mx = fmaxf(mx, v[i]);
    float s = 0.f;
#pragma unroll
    for (int i = 0; i < 96; i++) { v[i] = expf(v[i] - mx); s += v[i]; }
    float inv = 1.0f / s;
#pragma unroll
    for (int j = 0; j < 12; j++) {
        short8 w;
#pragma unroll
        for (int x = 0; x < 8; x++)
            w[x] = (short)__bfloat16_as_ushort(__float2bfloat16(v[j * 8 + x] * inv));
        *(short8*)&p[j * 8] = w;
    }
}

// ---- context[nh,96,48] += sum_l kh[l,96]*vh[l,48] ----
__global__ __launch_bounds__(256) void context_k(const bf16* __restrict__ Kt,
                                                 const bf16* __restrict__ Vt,
                                                 float* __restrict__ ctx) {
    __shared__ float ks[32][96];
    __shared__ float vs[32][48];
    int nh = blockIdx.y;
    int n = nh >> 3, h = nh & 7;
    int t = threadIdx.x;
    const unsigned short* kp = (const unsigned short*)Kt;
    const unsigned short* vp = (const unsigned short*)Vt;
    int a = t >> 4, bq = t & 15;
    float acc[6][3];
#pragma unroll
    for (int i = 0; i < 6; i++)
#pragma unroll
        for (int j = 0; j < 3; j++) acc[i][j] = 0.f;
    int l0 = blockIdx.x * 448;
    for (int ls = l0; ls < l0 + 448; ls += 32) {
        __syncthreads();
#pragma unroll
        for (int j = 0; j < 6; j++) {
            int e = t + 256 * j;
            int row = e / 48, cp = e % 48;
            unsigned u = *(const unsigned*)&kp[((size_t)(n * 3136 + ls + row)) * 768 + h * 96 + cp * 2];
            ks[row][cp * 2] = bfbits2f((unsigned short)(u & 0xffff));
            ks[row][cp * 2 + 1] = bfbits2f((unsigned short)(u >> 16));
        }
#pragma unroll
        for (int j = 0; j < 3; j++) {
            int e = t + 256 * j;
            int row = e / 24, cp = e % 24;
            unsigned u = *(const unsigned*)&vp[((size_t)(n * 3136 + ls + row)) * 384 + h * 48 + cp * 2];
            vs[row][cp * 2] = bfbits2f((unsigned short)(u & 0xffff));
            vs[row][cp * 2 + 1] = bfbits2f((unsigned short)(u >> 16));
        }
        __syncthreads();
        for (int ll = 0; ll < 32; ll++) {
            float kv[6], vv[3];
#pragma unroll
            for (int i = 0; i < 6; i++) kv[i] = ks[ll][a * 6 + i];
#pragma unroll
            for (int j = 0; j < 3; j++) vv[j] = vs[ll][bq * 3 + j];
#pragma unroll
            for (int i = 0; i < 6; i++)
#pragma unroll
                for (int j = 0; j < 3; j++) acc[i][j] += kv[i] * vv[j];
        }
    }
    float* cb = ctx + (size_t)nh * 4608;
#pragma unroll
    for (int i = 0; i < 6; i++)
#pragma unroll
        for (int j = 0; j < 3; j++)
            atomicAdd(&cb[(a * 6 + i) * 48 + bq * 3 + j], acc[i][j]);
}

// ---- att_t[token,48-slice] = qh[token,96] @ ctx[96,48], bf16 out ----
__global__ __launch_bounds__(256) void att_k(const float* __restrict__ ctx,
                                             const bf16* __restrict__ Qt,
                                             bf16* __restrict__ att) {
    __shared__ float cs[4608];
    int nh = blockIdx.y;
    int n = nh >> 3, h = nh & 7;
    for (int j = threadIdx.x; j < 4608; j += 256) cs[j] = ctx[(size_t)nh * 4608 + j];
    __syncthreads();
    int l = blockIdx.x * 256 + threadIdx.x;
    if (l >= 3136) return;
    const unsigned short* qp = (const unsigned short*)Qt + ((size_t)(n * 3136 + l)) * 768 + h * 96;
    float qv[96];
#pragma unroll
    for (int j = 0; j < 12; j++) {
        short8 w = *(const short8*)&qp[j * 8];
#pragma unroll
        for (int x = 0; x < 8; x++) qv[j * 8 + x] = bfbits2f((unsigned short)w[x]);
    }
    unsigned short ov[48];
#pragma unroll
    for (int vb = 0; vb < 12; vb++) {
        f32x4 s;
        s[0] = s[1] = s[2] = s[3] = 0.f;
        for (int k = 0; k < 96; k++) {
            f32x4 c4 = *(const f32x4*)&cs[k * 48 + vb * 4];
            float q = qv[k];
#pragma unroll
            for (int x = 0; x < 4; x++) s[x] += c4[x] * q;
        }
#pragma unroll
        for (int x = 0; x < 4; x++)
            ov[vb * 4 + x] = __bfloat16_as_ushort(__float2bfloat16(s[x]));
    }
    unsigned short* op = (unsigned short*)att + ((size_t)n * 3200 + l) * 384 + h * 48;
#pragma unroll
    for (int j = 0; j < 6; j++) *(short8*)&op[j * 8] = *(short8*)&ov[j * 8];
}

extern "C" void kernel_launch(void* const* d_in, const int* in_sizes, int n_in,
                              void* d_out, int out_size, void* d_ws, size_t ws_size,
                              hipStream_t stream) {
    (void)in_sizes; (void)n_in; (void)out_size; (void)ws_size;
    const float* x     = (const float*)d_in[0];
    const float* ln1_g = (const float*)d_in[1];
    const float* ln1_b = (const float*)d_in[2];
    const float* Wk    = (const float*)d_in[3];
    const float* bk    = (const float*)d_in[4];
    const float* Wq    = (const float*)d_in[5];
    const float* bq    = (const float*)d_in[6];
    const float* Wv    = (const float*)d_in[7];
    const float* bv    = (const float*)d_in[8];
    const float* Wr    = (const float*)d_in[9];
    const float* br    = (const float*)d_in[10];
    const float* ln2_g = (const float*)d_in[11];
    const float* ln2_b = (const float*)d_in[12];
    const float* W1    = (const float*)d_in[13];
    const float* b1    = (const float*)d_in[14];
    const float* W2    = (const float*)d_in[15];
    const float* b2    = (const float*)d_in[16];

    const int Nb = 16, L = 3136;
    const size_t LD = (size_t)L * 768;
    const size_t sz77 = (size_t)50176 * 768 * 2;

    char* w = (char*)d_ws;
    size_t off = 0;
    auto alloc = [&](size_t bytes) {
        char* p = w + off;
        off = (off + bytes + 255) & ~(size_t)255;
        return p;
    };
    bf16* Ybf  = (bf16*)alloc(sz77);                       // Hbf rgn 0
    bf16* Xt   = (bf16*)alloc(sz77);                       // Hbf rgn 1 (ctx/pm/ps alias)
    bf16* Kt   = (bf16*)alloc(sz77);                       // Hbf rgn 2
    bf16* Qt   = (bf16*)alloc(sz77);                       // Hbf rgn 3
    bf16* Vt   = (bf16*)alloc((size_t)50176 * 384 * 2);    // Y2bf rgn
    bf16* attb = (bf16*)alloc((size_t)16 * 3200 * 384 * 2);
    bf16* x1   = (bf16*)alloc(sz77);                       // survives to the end
    bf16* Wkqv_bf = (bf16*)alloc((size_t)1920 * 768 * 2);
    bf16* Wr_bf = (bf16*)alloc((size_t)768 * 384 * 2);
    bf16* W1_bf = (bf16*)alloc((size_t)3072 * 768 * 2);
    bf16* W2_bf = (bf16*)alloc((size_t)768 * 3072 * 2);
    float* bkqv = (float*)alloc((size_t)1920 * 4);
    // ctx/pm/ps alias Xt (free after KQV gemm; dead before MLP1's Hbf write)
    float* ctx = (float*)Xt;
    float* pm  = (float*)(Xt + 2359296);   // 4.5 MiB in
    float* ps  = (float*)(Xt + 2621440);
    bf16* Hbf  = Ybf;    // [50176,3072] spans rgns 0-3
    bf16* Y2bf = Vt;     // spills into attb (dead by then)

    auto castw = [&](const float* s, bf16* dp, int n) {
        cast_kernel<<<(n + 255) / 256, 256, 0, stream>>>(s, dp, n);
    };
    castw(Wk, Wkqv_bf, 768 * 768);
    castw(Wq, Wkqv_bf + 768 * 768, 768 * 768);
    castw(Wv, Wkqv_bf + 1536 * 768, 384 * 768);
    castw(Wr, Wr_bf, 768 * 384);
    castw(W1, W1_bf, 3072 * 768);
    castw(W2, W2_bf, 768 * 3072);
    bias_cat<<<8, 256, 0, stream>>>(bk, bq, bv, bkqv);

    // LN1: x -> Ybf, then transpose -> Xt [n*3136, 768]
    ln_f32<<<Nb * L, 192, 0, stream>>>(x, ln1_g, ln1_b, Ybf);
    transp_k<<<dim3(49, 12, 16), 256, 0, stream>>>(Ybf, Xt);

    dim3 blk(256);
    // fused K/Q/V projection: [50176,1920] = Xt @ Wkqv^T, split-store
    gemm_nk<0><<<dim3(15, 392, 1), blk, 0, stream>>>(
        Xt, Wkqv_bf, bkqv, nullptr, Kt, Qt, Vt, 50176, 1920, 768, 0, 0, 0);

    softk_part<<<dim3(8, 48), blk, 0, stream>>>(Kt, pm, ps);
    softk_fin<<<dim3(8, 48), blk, 0, stream>>>(Kt, pm, ps);
    softq_k<<<1568, blk, 0, stream>>>(Qt);

    hipMemsetAsync(ctx, 0, (size_t)128 * 4608 * 4, stream);
    context_k<<<dim3(7, 128), blk, 0, stream>>>(Kt, Vt, ctx);
    att_k<<<dim3(13, 128), blk, 0, stream>>>(ctx, Qt, attb);

    // Wr projection + residual (flat add) -> x1 bf16
    gemm_nk<1><<<dim3(25, 6, 16), blk, 0, stream>>>(
        Wr_bf, attb, br, x, x1, nullptr, nullptr, 768, 3136, 384,
        (long)3200 * 384, (long)LD, (long)LD);

    // LN2: x1 -> Y2bf
    ln_bf<<<Nb * L, 192, 0, stream>>>(x1, ln2_g, ln2_b, Y2bf);

    // MLP1: [50176,3072] = Y2 @ W1^T, +b1, gelu, bf16
    gemm_nk<2><<<dim3(24, 392, 1), blk, 0, stream>>>(
        Y2bf, W1_bf, b1, nullptr, Hbf, nullptr, nullptr, 50176, 3072, 768, 0, 0, 0);
    // MLP2: d_out(f32) = H @ W2^T + b2 + x1
    gemm_nk<3><<<dim3(6, 392, 1), blk, 0, stream>>>(
        Hbf, W2_bf, b2, x1, d_out, nullptr, nullptr, 50176, 768, 3072, 0, 0, 0);
}

// Round 5
// 1391.460 us; speedup vs baseline: 1.8055x; 1.1606x over previous
//
#include <hip/hip_runtime.h>
#include <hip/hip_bf16.h>

using bf16 = __hip_bfloat16;
typedef __attribute__((ext_vector_type(8))) short short8;
typedef __attribute__((ext_vector_type(4))) short short4v;
typedef __attribute__((ext_vector_type(4))) float f32x4;

__device__ __forceinline__ float bfbits2f(unsigned short h) {
    unsigned v = (unsigned)h << 16;
    return __uint_as_float(v);
}

__device__ __forceinline__ void gload16(const void* g, void* l) {
    __builtin_amdgcn_global_load_lds(
        (const __attribute__((address_space(1))) unsigned int*)g,
        (__attribute__((address_space(3))) unsigned int*)l, 16, 0, 0);
}

// tanh-form GELU: ~8 VALU; |diff vs exact erf-GELU| <= ~3e-3
__device__ __forceinline__ float gelu_fast(float x) {
    float x2 = x * x;
    float u = x * __builtin_fmaf(0.07135481f, x2, 1.59576912f);
    float e = __expf(u);
    return x - x * __builtin_amdgcn_rcpf(e + 1.0f);
}

// ---- block reduce over 3 waves (192 threads) ----
__device__ __forceinline__ float blk_sum3(float v, float* red) {
#pragma unroll
    for (int o = 32; o > 0; o >>= 1) v += __shfl_down(v, o, 64);
    int wv = threadIdx.x >> 6;
    __syncthreads();
    if ((threadIdx.x & 63) == 0) red[wv] = v;
    __syncthreads();
    return red[0] + red[1] + red[2];
}

// ---- LayerNorm over D=768, one block per row, f32 in -> bf16 out ----
__global__ __launch_bounds__(192) void ln_f32(const float* __restrict__ x,
                                              const float* __restrict__ g,
                                              const float* __restrict__ b,
                                              bf16* __restrict__ y) {
    __shared__ float red[3];
    size_t base = (size_t)blockIdx.x * 768;
    int t = threadIdx.x;
    float4 v = *(const float4*)&x[base + t * 4];
    float s = blk_sum3(v.x + v.y + v.z + v.w, red);
    float mean = s * (1.0f / 768.0f);
    float d0 = v.x - mean, d1 = v.y - mean, d2 = v.z - mean, d3 = v.w - mean;
    float sq = blk_sum3(d0 * d0 + d1 * d1 + d2 * d2 + d3 * d3, red);
    float rstd = rsqrtf(sq * (1.0f / 768.0f) + 1e-6f);
    float4 gv = *(const float4*)&g[t * 4];
    float4 bv = *(const float4*)&b[t * 4];
    short4v o;
    o[0] = (short)__bfloat16_as_ushort(__float2bfloat16(d0 * rstd * gv.x + bv.x));
    o[1] = (short)__bfloat16_as_ushort(__float2bfloat16(d1 * rstd * gv.y + bv.y));
    o[2] = (short)__bfloat16_as_ushort(__float2bfloat16(d2 * rstd * gv.z + bv.z));
    o[3] = (short)__bfloat16_as_ushort(__float2bfloat16(d3 * rstd * gv.w + bv.w));
    *(short4v*)&((unsigned short*)y)[base + t * 4] = o;
}

// ---- LayerNorm, bf16 in -> bf16 out ----
__global__ __launch_bounds__(192) void ln_bf(const bf16* __restrict__ x,
                                             const float* __restrict__ g,
                                             const float* __restrict__ b,
                                             bf16* __restrict__ y) {
    __shared__ float red[3];
    size_t base = (size_t)blockIdx.x * 768;
    int t = threadIdx.x;
    short4v w = *(const short4v*)&((const unsigned short*)x)[base + t * 4];
    float v0 = bfbits2f((unsigned short)w[0]), v1 = bfbits2f((unsigned short)w[1]);
    float v2 = bfbits2f((unsigned short)w[2]), v3 = bfbits2f((unsigned short)w[3]);
    float s = blk_sum3(v0 + v1 + v2 + v3, red);
    float mean = s * (1.0f / 768.0f);
    float d0 = v0 - mean, d1 = v1 - mean, d2 = v2 - mean, d3 = v3 - mean;
    float sq = blk_sum3(d0 * d0 + d1 * d1 + d2 * d2 + d3 * d3, red);
    float rstd = rsqrtf(sq * (1.0f / 768.0f) + 1e-6f);
    float4 gv = *(const float4*)&g[t * 4];
    float4 bv = *(const float4*)&b[t * 4];
    short4v o;
    o[0] = (short)__bfloat16_as_ushort(__float2bfloat16(d0 * rstd * gv.x + bv.x));
    o[1] = (short)__bfloat16_as_ushort(__float2bfloat16(d1 * rstd * gv.y + bv.y));
    o[2] = (short)__bfloat16_as_ushort(__float2bfloat16(d2 * rstd * gv.z + bv.z));
    o[3] = (short)__bfloat16_as_ushort(__float2bfloat16(d3 * rstd * gv.w + bv.w));
    *(short4v*)&((unsigned short*)y)[base + t * 4] = o;
}

// ---- f32 -> bf16 cast ----
__global__ __launch_bounds__(256) void cast_kernel(const float* __restrict__ s,
                                                   bf16* __restrict__ d, int n) {
    int i = blockIdx.x * 256 + threadIdx.x;
    if (i < n) d[i] = __float2bfloat16(s[i]);
}

// ---- concat K/Q/V biases into one [1920] f32 buffer ----
__global__ __launch_bounds__(256) void bias_cat(const float* __restrict__ bk,
                                                const float* __restrict__ bq,
                                                const float* __restrict__ bv,
                                                float* __restrict__ o) {
    int i = blockIdx.x * 256 + threadIdx.x;
    if (i < 768) o[i] = bk[i];
    else if (i < 1536) o[i] = bq[i - 768];
    else if (i < 1920) o[i] = bv[i - 1536];
}

// ---- bf16 transpose per batch: Y [768,3136] -> Xt [3136,768] ----
__global__ __launch_bounds__(256) void transp_k(const bf16* __restrict__ Y,
                                                bf16* __restrict__ Xt) {
    __shared__ unsigned short tile[64][65];
    const size_t LD = (size_t)768 * 3136;
    int n = blockIdx.z;
    int l0 = blockIdx.x * 64, d0 = blockIdx.y * 64;
    const unsigned short* Yp = (const unsigned short*)Y + (size_t)n * LD;
    unsigned short* Xp = (unsigned short*)Xt + (size_t)n * LD;
    int t = threadIdx.x;
#pragma unroll
    for (int j = 0; j < 2; j++) {
        int e = t + 256 * j;
        int dd = e >> 3, lg = (e & 7) * 8;
        short8 v = *(const short8*)&Yp[(size_t)(d0 + dd) * 3136 + l0 + lg];
#pragma unroll
        for (int u = 0; u < 8; u++) tile[dd][lg + u] = (unsigned short)v[u];
    }
    __syncthreads();
#pragma unroll
    for (int j = 0; j < 2; j++) {
        int e = t + 256 * j;
        int ll = e >> 3, dg = (e & 7) * 8;
        short8 v;
#pragma unroll
        for (int u = 0; u < 8; u++) v[u] = (short)tile[dg + u][ll];
        *(short8*)&Xp[(size_t)(l0 + ll) * 768 + d0 + dg] = v;
    }
}

// ============ 256x256 BK=64 double-buffered GEMM, counted vmcnt ============
// C[M,N] = A[M,K] * B[N,K]^T. 512 threads = 8 waves (2M x 4N). LDS 128 KiB dyn.
// MODE 0: split-KQV bf16 (N padded; store col<1920), +bias[col]
// MODE 2: C0=bf16, gelu(v + bias[col])
// MODE 3: C0=f32,  v + bias[col] + residb(bf16)[flat]
template <int MODE>
__global__ __launch_bounds__(512, 2) void gemm256(
    const bf16* __restrict__ A, const bf16* __restrict__ B,
    const float* __restrict__ bias, const void* __restrict__ resid,
    void* __restrict__ C0, void* __restrict__ C1, void* __restrict__ C2,
    int M, int N, int K) {
    extern __shared__ char smem[];
    const int tid = threadIdx.x;
    const int lane = tid & 63, wave = tid >> 6;

    // XCD-chunked bijective swizzle; bn fastest within a chunk
    const int nbn = gridDim.x;
    const int nwg = nbn * gridDim.y;
    const int orig = blockIdx.y * nbn + blockIdx.x;
    const int qq = nwg >> 3, rm = nwg & 7;
    const int xcd = orig & 7, pos = orig >> 3;
    const int work = (xcd < rm ? xcd * (qq + 1) : rm * (qq + 1) + (xcd - rm) * qq) + pos;
    const int bn = work % nbn, bm = work / nbn;

    const int wm = (wave >> 2) * 128, wn = (wave & 3) * 64;
    const int frow = lane & 15, fsb = lane >> 4, fxr = frow & 7;
    const int srow = lane >> 3, sslot = (lane & 7) ^ srow;
    const size_t rowB = (size_t)K * 2;
    const char* Ap = (const char*)A + (size_t)(bm * 256 + wave * 32 + srow) * rowB + sslot * 16;
    const char* Bp = (const char*)B + (size_t)(bn * 256 + wave * 32 + srow) * rowB + sslot * 16;
    char* lA = smem + wave * 32 * 128;           // + c*1024 + p*65536
    char* lB = smem + 32768 + wave * 32 * 128;

    f32x4 acc[8][4];
#pragma unroll
    for (int mi = 0; mi < 8; mi++)
#pragma unroll
        for (int ni = 0; ni < 4; ni++)
#pragma unroll
            for (int r = 0; r < 4; r++) acc[mi][ni][r] = 0.0f;

    auto stage = [&](int kt, int p) {
#pragma unroll
        for (int c = 0; c < 4; c++) {
            gload16(Ap + (size_t)c * 8 * rowB + (size_t)kt * 2, lA + p * 65536 + c * 1024);
            gload16(Bp + (size_t)c * 8 * rowB + (size_t)kt * 2, lB + p * 65536 + c * 1024);
        }
    };
    const int nt = K >> 6;   // K in {768, 3072}: nt >= 12
    stage(0, 0);
    stage(64, 1);
    for (int t = 0; t < nt; ++t) {
        // Drain this tile's 8 loads. Steady state: 16 outstanding (tiles t,t+1),
        // vmcnt(8) completes tile t, leaves t+1 in flight. LAST tile: only its
        // own 8 outstanding -> vmcnt(8) would be a no-op race; must drain to 0.
        if (t == nt - 1)
            asm volatile("s_waitcnt vmcnt(0)" ::: "memory");
        else
            asm volatile("s_waitcnt vmcnt(8)" ::: "memory");
        __builtin_amdgcn_s_barrier();        // extend per-wave guarantee block-wide
        asm volatile("" ::: "memory");
        const bf16* As = (const bf16*)(smem + (t & 1) * 65536);
        const bf16* Bs = (const bf16*)(smem + (t & 1) * 65536 + 32768);
#pragma unroll
        for (int k2 = 0; k2 < 2; k2++) {
            const int ko = ((k2 * 4 + fsb) ^ fxr) << 3;
            short8 bfv[4];
#pragma unroll
            for (int ni = 0; ni < 4; ni++)
                bfv[ni] = *(const short8*)&Bs[(wn + ni * 16 + frow) * 64 + ko];
#pragma unroll
            for (int half = 0; half < 2; half++) {
                short8 af[4];
#pragma unroll
                for (int i = 0; i < 4; i++)
                    af[i] = *(const short8*)&As[(wm + (half * 4 + i) * 16 + frow) * 64 + ko];
#pragma unroll
                for (int i = 0; i < 4; i++)
#pragma unroll
                    for (int ni = 0; ni < 4; ni++)
                        acc[half * 4 + i][ni] = __builtin_amdgcn_mfma_f32_16x16x32_bf16(
                            af[i], bfv[ni], acc[half * 4 + i][ni], 0, 0, 0);
            }
        }
        asm volatile("" ::: "memory");
        __builtin_amdgcn_s_barrier();        // all reads of buf (t&1) complete
        if (t + 2 < nt) stage((t + 2) * 64, t & 1);
    }

    const unsigned short* Rb = (const unsigned short*)resid;
#pragma unroll
    for (int mi = 0; mi < 8; mi++)
#pragma unroll
        for (int ni = 0; ni < 4; ni++)
#pragma unroll
            for (int r = 0; r < 4; r++) {
                int row = bm * 256 + wm + mi * 16 + fsb * 4 + r;
                int col = bn * 256 + wn + ni * 16 + frow;
                float v = acc[mi][ni][r];
                if (MODE == 0) {
                    if (col < 1920) {
                        float o = v + bias[col];
                        if (col < 768)
                            ((bf16*)C0)[(size_t)row * 768 + col] = __float2bfloat16(o);
                        else if (col < 1536)
                            ((bf16*)C1)[(size_t)row * 768 + col - 768] = __float2bfloat16(o);
                        else
                            ((bf16*)C2)[(size_t)row * 384 + col - 1536] = __float2bfloat16(o);
                    }
                } else if (MODE == 2) {
                    ((bf16*)C0)[(size_t)row * N + col] =
                        __float2bfloat16(gelu_fast(v + bias[col]));
                } else {
                    size_t idx = (size_t)row * N + col;
                    ((float*)C0)[idx] = v + bias[col] + bfbits2f(Rb[idx]);
                }
            }
}

// ---- 128x128 GEMM (proven), kept for the Wr projection ----
// MODE 1: C0=bf16, v + bias[row] + residf(f32)[flat]
template <int MODE>
__global__ __launch_bounds__(256) void gemm_nk(
    const bf16* __restrict__ A, const bf16* __restrict__ B,
    const float* __restrict__ bias, const void* __restrict__ resid,
    void* __restrict__ C0, int M, int N, int K, long sB, long sC, long sR) {
    __shared__ bf16 As[128 * 64];
    __shared__ bf16 Bs[128 * 64];
    const int tid = threadIdx.x;
    const int lane = tid & 63, wave = tid >> 6;
    const int nbn = gridDim.x;
    const int nwg = nbn * gridDim.y;
    const int orig = blockIdx.y * nbn + blockIdx.x;
    const int qq = nwg >> 3, rm = nwg & 7;
    const int xcd = orig & 7, pos = orig >> 3;
    const int work = (xcd < rm ? xcd * (qq + 1) : rm * (qq + 1) + (xcd - rm) * qq) + pos;
    const int bn = work % nbn, bm = work / nbn;
    const int bz = blockIdx.z;

    const int wm = (wave >> 1) * 64, wn = (wave & 1) * 64;
    const int frow = lane & 15, fsb = lane >> 4, fxr = frow & 7;
    const int srow = lane >> 3, sslot = (lane & 7) ^ srow;
    const size_t rowB = (size_t)K * 2;
    const char* Ap = (const char*)A +
        ((size_t)bm * 128 + wave * 32 + srow) * rowB + (size_t)sslot * 16;
    const char* Bp = (const char*)(B + (size_t)bz * sB) +
        ((size_t)bn * 128 + wave * 32 + srow) * rowB + (size_t)sslot * 16;

    f32x4 acc[4][4];
#pragma unroll
    for (int mi = 0; mi < 4; mi++)
#pragma unroll
        for (int ni = 0; ni < 4; ni++)
#pragma unroll
            for (int r = 0; r < 4; r++) acc[mi][ni][r] = 0.0f;

    for (int kt = 0; kt < K; kt += 64) {
#pragma unroll
        for (int c = 0; c < 4; c++) {
            gload16(Ap + (size_t)c * 8 * rowB + (size_t)kt * 2, &As[(wave * 4 + c) * 512]);
            gload16(Bp + (size_t)c * 8 * rowB + (size_t)kt * 2, &Bs[(wave * 4 + c) * 512]);
        }
        __syncthreads();
#pragma unroll
        for (int k2 = 0; k2 < 2; k2++) {
            short8 af[4], bfv[4];
#pragma unroll
            for (int mi = 0; mi < 4; mi++) {
                int r = wm + mi * 16 + frow;
                af[mi] = *(const short8*)&As[r * 64 + (((k2 * 4 + fsb) ^ fxr) << 3)];
            }
#pragma unroll
            for (int ni = 0; ni < 4; ni++) {
                int r = wn + ni * 16 + frow;
                bfv[ni] = *(const short8*)&Bs[r * 64 + (((k2 * 4 + fsb) ^ fxr) << 3)];
            }
#pragma unroll
            for (int mi = 0; mi < 4; mi++)
#pragma unroll
                for (int ni = 0; ni < 4; ni++)
                    acc[mi][ni] = __builtin_amdgcn_mfma_f32_16x16x32_bf16(
                        af[mi], bfv[ni], acc[mi][ni], 0, 0, 0);
        }
        __syncthreads();
    }

    const float* Rf = (const float*)resid + (size_t)bz * sR;
#pragma unroll
    for (int mi = 0; mi < 4; mi++)
#pragma unroll
        for (int ni = 0; ni < 4; ni++)
#pragma unroll
            for (int r = 0; r < 4; r++) {
                int row = bm * 128 + wm + mi * 16 + (fsb << 2) + r;
                int col = bn * 128 + wn + ni * 16 + frow;
                if (col < N) {
                    float v = acc[mi][ni][r];
                    size_t idx = (size_t)row * N + col;
                    bf16* Cb = (bf16*)C0 + (size_t)bz * sC;
                    Cb[idx] = __float2bfloat16(v + bias[row] + Rf[idx]);
                }
            }
}

// ---- fused context: ctx_raw[nh,96,48] = sum_l exp(k[l,96]) outer v[l,48];
//      S[nh,96] = sum_l exp(k).  Raw (pre-softmax) Kt in. ----
__global__ __launch_bounds__(256) void context_k(const bf16* __restrict__ Kt,
                                                 const bf16* __restrict__ Vt,
                                                 float* __restrict__ ctx,
                                                 float* __restrict__ Sf) {
    __shared__ float ks[32][96];
    __shared__ float vs[32][48];
    int nh = blockIdx.y;
    int n = nh >> 3, h = nh & 7;
    int t = threadIdx.x;
    const unsigned short* kp = (const unsigned short*)Kt;
    const unsigned short* vp = (const unsigned short*)Vt;
    int a = t >> 4, bq = t & 15;
    float acc[6][3];
    float sacc[6];
#pragma unroll
    for (int i = 0; i < 6; i++) {
        sacc[i] = 0.f;
#pragma unroll
        for (int j = 0; j < 3; j++) acc[i][j] = 0.f;
    }
    int l0 = blockIdx.x * 448;
    for (int ls = l0; ls < l0 + 448; ls += 32) {
        __syncthreads();
#pragma unroll
        for (int j = 0; j < 6; j++) {
            int e = t + 256 * j;
            int row = e / 48, cp = e % 48;
            unsigned u = *(const unsigned*)&kp[((size_t)(n * 3136 + ls + row)) * 768 + h * 96 + cp * 2];
            ks[row][cp * 2] = __expf(bfbits2f((unsigned short)(u & 0xffff)));
            ks[row][cp * 2 + 1] = __expf(bfbits2f((unsigned short)(u >> 16)));
        }
#pragma unroll
        for (int j = 0; j < 3; j++) {
            int e = t + 256 * j;
            int row = e / 24, cp = e % 24;
            unsigned u = *(const unsigned*)&vp[((size_t)(n * 3136 + ls + row)) * 384 + h * 48 + cp * 2];
            vs[row][cp * 2] = bfbits2f((unsigned short)(u & 0xffff));
            vs[row][cp * 2 + 1] = bfbits2f((unsigned short)(u >> 16));
        }
        __syncthreads();
        for (int ll = 0; ll < 32; ll++) {
            float kv[6], vv[3];
#pragma unroll
            for (int i = 0; i < 6; i++) { kv[i] = ks[ll][a * 6 + i]; sacc[i] += kv[i]; }
#pragma unroll
            for (int j = 0; j < 3; j++) vv[j] = vs[ll][bq * 3 + j];
#pragma unroll
            for (int i = 0; i < 6; i++)
#pragma unroll
                for (int j = 0; j < 3; j++) acc[i][j] += kv[i] * vv[j];
        }
    }
    float* cb = ctx + (size_t)nh * 4608;
#pragma unroll
    for (int i = 0; i < 6; i++) {
#pragma unroll
        for (int j = 0; j < 3; j++)
            atomicAdd(&cb[(a * 6 + i) * 48 + bq * 3 + j], acc[i][j]);
        if (bq == 0) atomicAdd(&Sf[(size_t)nh * 96 + a * 6 + i], sacc[i]);
    }
}

// ---- normalize context rows by S ----
__global__ __launch_bounds__(256) void ctx_fin(float* __restrict__ ctx,
                                               const float* __restrict__ Sf) {
    int nh = blockIdx.x;
    __shared__ float sinv[96];
    if (threadIdx.x < 96) sinv[threadIdx.x] = 1.0f / Sf[(size_t)nh * 96 + threadIdx.x];
    __syncthreads();
    for (int e = threadIdx.x; e < 4608; e += 256)
        ctx[(size_t)nh * 4608 + e] *= sinv[e / 48];
}

// ---- att: per token, softmax(96 raw q) then ctx^T @ q, bf16 out ----
__global__ __launch_bounds__(256) void att_k(const float* __restrict__ ctx,
                                             const bf16* __restrict__ Qt,
                                             bf16* __restrict__ att) {
    __shared__ float cs[4608];
    int nh = blockIdx.y;
    int n = nh >> 3, h = nh & 7;
    for (int j = threadIdx.x; j < 4608; j += 256) cs[j] = ctx[(size_t)nh * 4608 + j];
    __syncthreads();
    int l = blockIdx.x * 256 + threadIdx.x;
    if (l >= 3136) return;
    const unsigned short* qp = (const unsigned short*)Qt + ((size_t)(n * 3136 + l)) * 768 + h * 96;
    float qv[96];
    float s = 0.f;
#pragma unroll
    for (int j = 0; j < 12; j++) {
        short8 w = *(const short8*)&qp[j * 8];
#pragma unroll
        for (int x = 0; x < 8; x++) {
            float e = __expf(bfbits2f((unsigned short)w[x]));
            qv[j * 8 + x] = e;
            s += e;
        }
    }
    float inv = 1.0f / s;
    unsigned short ov[48];
#pragma unroll
    for (int vb = 0; vb < 12; vb++) {
        f32x4 acc4;
        acc4[0] = acc4[1] = acc4[2] = acc4[3] = 0.f;
        for (int k = 0; k < 96; k++) {
            f32x4 c4 = *(const f32x4*)&cs[k * 48 + vb * 4];
            float q = qv[k];
#pragma unroll
            for (int x = 0; x < 4; x++) acc4[x] += c4[x] * q;
        }
#pragma unroll
        for (int x = 0; x < 4; x++)
            ov[vb * 4 + x] = __bfloat16_as_ushort(__float2bfloat16(acc4[x] * inv));
    }
    unsigned short* op = (unsigned short*)att + ((size_t)n * 3200 + l) * 384 + h * 48;
#pragma unroll
    for (int j = 0; j < 6; j++) *(short8*)&op[j * 8] = *(short8*)&ov[j * 8];
}

extern "C" void kernel_launch(void* const* d_in, const int* in_sizes, int n_in,
                              void* d_out, int out_size, void* d_ws, size_t ws_size,
                              hipStream_t stream) {
    (void)in_sizes; (void)n_in; (void)out_size; (void)ws_size;
    const float* x     = (const float*)d_in[0];
    const float* ln1_g = (const float*)d_in[1];
    const float* ln1_b = (const float*)d_in[2];
    const float* Wk    = (const float*)d_in[3];
    const float* bk    = (const float*)d_in[4];
    const float* Wq    = (const float*)d_in[5];
    const float* bq    = (const float*)d_in[6];
    const float* Wv    = (const float*)d_in[7];
    const float* bv    = (const float*)d_in[8];
    const float* Wr    = (const float*)d_in[9];
    const float* br    = (const float*)d_in[10];
    const float* ln2_g = (const float*)d_in[11];
    const float* ln2_b = (const float*)d_in[12];
    const float* W1    = (const float*)d_in[13];
    const float* b1    = (const float*)d_in[14];
    const float* W2    = (const float*)d_in[15];
    const float* b2    = (const float*)d_in[16];

    const int Nb = 16, L = 3136;
    const size_t LD = (size_t)L * 768;
    const size_t sz77 = (size_t)50176 * 768 * 2;

    char* w = (char*)d_ws;
    size_t off = 0;
    auto alloc = [&](size_t bytes) {
        char* p = w + off;
        off = (off + bytes + 255) & ~(size_t)255;
        return p;
    };
    bf16* Ybf  = (bf16*)alloc(sz77);                       // Hbf rgn 0
    bf16* Xt   = (bf16*)alloc(sz77);                       // Hbf rgn 1 (ctx/S alias)
    bf16* Kt   = (bf16*)alloc(sz77);                       // Hbf rgn 2
    bf16* Qt   = (bf16*)alloc(sz77);                       // Hbf rgn 3
    bf16* Vt   = (bf16*)alloc((size_t)50176 * 384 * 2);    // Y2bf rgn
    bf16* attb = (bf16*)alloc((size_t)16 * 3200 * 384 * 2);
    bf16* x1   = (bf16*)alloc(sz77);
    bf16* Wkqv_bf = (bf16*)alloc((size_t)2048 * 768 * 2);  // padded to 2048 rows
    bf16* Wr_bf = (bf16*)alloc((size_t)768 * 384 * 2);
    bf16* W1_bf = (bf16*)alloc((size_t)3072 * 768 * 2);
    bf16* W2_bf = (bf16*)alloc((size_t)768 * 3072 * 2);
    float* bkqv = (float*)alloc((size_t)1920 * 4);
    // ctx + S alias Xt (Xt dead after KQV gemm; region dead before MLP1)
    float* ctx = (float*)Xt;
    float* Sf  = (float*)((char*)Xt + 4718592);
    bf16* Hbf  = Ybf;    // [50176,3072] spans rgns 0-3
    bf16* Y2bf = Vt;     // spills into attb (dead by then)

    auto castw = [&](const float* s, bf16* dp, int n) {
        cast_kernel<<<(n + 255) / 256, 256, 0, stream>>>(s, dp, n);
    };
    hipMemsetAsync(Wkqv_bf + (size_t)1920 * 768, 0, (size_t)128 * 768 * 2, stream);
    castw(Wk, Wkqv_bf, 768 * 768);
    castw(Wq, Wkqv_bf + 768 * 768, 768 * 768);
    castw(Wv, Wkqv_bf + 1536 * 768, 384 * 768);
    castw(Wr, Wr_bf, 768 * 384);
    castw(W1, W1_bf, 3072 * 768);
    castw(W2, W2_bf, 768 * 3072);
    bias_cat<<<8, 256, 0, stream>>>(bk, bq, bv, bkqv);

    hipFuncSetAttribute((const void*)gemm256<0>,
                        hipFuncAttributeMaxDynamicSharedMemorySize, 131072);
    hipFuncSetAttribute((const void*)gemm256<2>,
                        hipFuncAttributeMaxDynamicSharedMemorySize, 131072);
    hipFuncSetAttribute((const void*)gemm256<3>,
                        hipFuncAttributeMaxDynamicSharedMemorySize, 131072);

    // LN1: x -> Ybf, then transpose -> Xt [n*3136, 768]
    ln_f32<<<Nb * L, 192, 0, stream>>>(x, ln1_g, ln1_b, Ybf);
    transp_k<<<dim3(49, 12, 16), 256, 0, stream>>>(Ybf, Xt);

    // fused K/Q/V projection (N padded 1920->2048), split-store raw K/Q/V
    gemm256<0><<<dim3(8, 196), 512, 131072, stream>>>(
        Xt, Wkqv_bf, bkqv, nullptr, Kt, Qt, Vt, 50176, 2048, 768);

    // attention middle: exp-fused context + normalize + softmax-fused att
    hipMemsetAsync(ctx, 0, 4718592 + 49152, stream);
    context_k<<<dim3(7, 128), 256, 0, stream>>>(Kt, Vt, ctx, Sf);
    ctx_fin<<<128, 256, 0, stream>>>(ctx, Sf);
    att_k<<<dim3(13, 128), 256, 0, stream>>>(ctx, Qt, attb);

    // Wr projection + residual (flat add, f32 x) -> x1 bf16
    gemm_nk<1><<<dim3(25, 6, 16), 256, 0, stream>>>(
        Wr_bf, attb, br, x, x1, 768, 3136, 384,
        (long)3200 * 384, (long)LD, (long)LD);

    // LN2: x1 -> Y2bf
    ln_bf<<<Nb * L, 192, 0, stream>>>(x1, ln2_g, ln2_b, Y2bf);

    // MLP1: [50176,3072] = Y2 @ W1^T, +b1, gelu, bf16
    gemm256<2><<<dim3(12, 196), 512, 131072, stream>>>(
        Y2bf, W1_bf, b1, nullptr, Hbf, nullptr, nullptr, 50176, 3072, 768);
    // MLP2: d_out(f32) = H @ W2^T + b2 + x1
    gemm256<3><<<dim3(3, 196), 512, 131072, stream>>>(
        Hbf, W2_bf, b2, x1, d_out, nullptr, nullptr, 50176, 768, 3072);
}